// Round 1
// 125.995 us; speedup vs baseline: 1.0215x; 1.0215x over previous
//
#include <hip/hip_runtime.h>

#define NROWS  32768
#define DIM    64
#define KCODES 1024
#define NELEM  (NROWS * DIM)   // 2097152
#define CHUNKS 16
#define CPC    (KCODES / CHUNKS)   // 64 codes per chunk-block

typedef float v2f __attribute__((ext_vector_type(2)));

// numpy-style pairwise sum of squares for n=64 contiguous fp32 (contraction
// OFF so the squared temps are not fused into the adds; matches jnp.sum(x*x)).
__device__ __forceinline__ float np_sumsq64(const float v[64]) {
#pragma clang fp contract(off)
  float r0 = v[0] * v[0];
  float r1 = v[1] * v[1];
  float r2 = v[2] * v[2];
  float r3 = v[3] * v[3];
  float r4 = v[4] * v[4];
  float r5 = v[5] * v[5];
  float r6 = v[6] * v[6];
  float r7 = v[7] * v[7];
#pragma unroll
  for (int i = 8; i < 64; i += 8) {
    r0 += v[i + 0] * v[i + 0];
    r1 += v[i + 1] * v[i + 1];
    r2 += v[i + 2] * v[i + 2];
    r3 += v[i + 3] * v[i + 3];
    r4 += v[i + 4] * v[i + 4];
    r5 += v[i + 5] * v[i + 5];
    r6 += v[i + 6] * v[i + 6];
    r7 += v[i + 7] * v[i + 7];
  }
  return ((r0 + r1) + (r2 + r3)) + ((r4 + r5) + (r6 + r7));
}

// Phase 1 (grid 128x256, one thread per row): init keys to +inf, per-row
// ||x||^2, per-code ||e||^2 (first 1024 threads).
__global__ __launch_bounds__(256) void vq_prep(const float* __restrict__ x,
                                               const float* __restrict__ w,
                                               float* __restrict__ se,
                                               float* __restrict__ sxv,
                                               unsigned long long* __restrict__ keys) {
  const int t = blockIdx.x * 256 + threadIdx.x;  // 0..32767
  keys[t] = ~0ull;

  float v[64];
  const float4* xr = (const float4*)(x + (size_t)t * DIM);
#pragma unroll
  for (int i = 0; i < 16; ++i) {
    float4 q = xr[i];
    v[4 * i + 0] = q.x; v[4 * i + 1] = q.y;
    v[4 * i + 2] = q.z; v[4 * i + 3] = q.w;
  }
  sxv[t] = np_sumsq64(v);

  if (t < KCODES) {
    const float4* wr = (const float4*)(w + (size_t)t * DIM);
#pragma unroll
    for (int i = 0; i < 16; ++i) {
      float4 q = wr[i];
      v[4 * i + 0] = q.x; v[4 * i + 1] = q.y;
      v[4 * i + 2] = q.z; v[4 * i + 3] = q.w;
    }
    se[t] = np_sumsq64(v);
  }
}

// Phase 2: distances + argmin. Grid 2048 = 128 row-groups x 16 K-chunks.
// Bijective XCD swizzle (8 XCDs, 2048 blocks -> 256/XCD): logical id
// l = (bid%8)*256 + bid/8 puts all 16 chunk-blocks of a row-group on ONE
// XCD, so each row-group's 64 KB of x is fetched from HBM once and served
// from that XCD's private L2 thereafter.
// xv[32] v2f is PINNED via empty asm: round-2 profiling showed VGPR_Count=44
// (< the 64 regs x needs), i.e. the compiler rematerialized the x loads
// inside the code loop, ~doubling VALU instructions. The "+v" asm makes the
// loaded values opaque definitions the remat pass cannot sink.
// d = fma(-2, dot, sx+se[c]) — bit-identical to ref's fl(fl(sx+se)-fl(2dot))
// since fl(2*dot) is exact. Distances positive -> fp32 bits monotone ->
// per-thread strict-< tracking (ascending c => lowest-index tie-break), then
// one u64 (dist_bits<<32)|c atomicMin per thread merges the 16 chunks with
// the same tie-break order.
__global__ __launch_bounds__(256, 4) void vq_dist(const float* __restrict__ x,
                                                  const float* __restrict__ w,
                                                  const float* __restrict__ se,
                                                  const float* __restrict__ sxv,
                                                  unsigned long long* __restrict__ keys) {
  const int bid = blockIdx.x;
  const int l = (bid & 7) * (2048 / 8) + (bid >> 3);  // XCD-bijective swizzle
  const int g = l >> 4;        // row-group 0..127
  const int chunk = l & 15;    // 0..15
  const int row = g * 256 + threadIdx.x;

  v2f xv[32];
  const float4* xr = (const float4*)(x + (size_t)row * DIM);
#pragma unroll
  for (int i = 0; i < 16; ++i) {
    float4 t = xr[i];
    xv[2 * i + 0] = (v2f){t.x, t.y};
    xv[2 * i + 1] = (v2f){t.z, t.w};
  }
#pragma unroll
  for (int i = 0; i < 32; ++i) asm volatile("" : "+v"(xv[i]));  // pin x in VGPRs
  const float sx = sxv[row];

  const int c0 = chunk * CPC;
  const float4* w4 = (const float4*)w;
  float bd = __builtin_inff();
  int bc = 0;

#pragma unroll 2
  for (int j = 0; j < CPC; ++j) {
    const int c = c0 + j;                      // wave-uniform -> scalar loads
    const float4* wr = w4 + (size_t)c * 16;
    v2f a0 = (v2f){0.f, 0.f}, a1 = (v2f){0.f, 0.f};
    v2f a2 = (v2f){0.f, 0.f}, a3 = (v2f){0.f, 0.f};
#pragma unroll
    for (int i = 0; i < 16; i += 2) {
      float4 t0 = wr[i];
      float4 t1 = wr[i + 1];
      a0 += (v2f){t0.x, t0.y} * xv[2 * i + 0];   // v_pk_fma_f32
      a1 += (v2f){t0.z, t0.w} * xv[2 * i + 1];
      a2 += (v2f){t1.x, t1.y} * xv[2 * i + 2];
      a3 += (v2f){t1.z, t1.w} * xv[2 * i + 3];
    }
    v2f s01 = a0 + a1;
    v2f s23 = a2 + a3;
    v2f s = s01 + s23;
    float dot = s.x + s.y;
    float d = fmaf(-2.0f, dot, sx + se[c]);
    if (d < bd) { bd = d; bc = c; }            // v_cmp + 2 cndmask
  }

  unsigned long long key =
      ((unsigned long long)__float_as_uint(bd) << 32) | (unsigned long long)(unsigned)bc;
  atomicMin(&keys[row], key);
}

// Phase 3 (grid 1024x256, 32 rows/block, 2 float4/thread -> 4 blocks/CU
// instead of the old 1/CU): decode key -> index, write indices (as float),
// STE quantized output x + fl(w - x), fp64 loss partial per block (no
// single-address atomic chain; vq_fin reduces the 1024 partials).
__global__ __launch_bounds__(256) void vq_out(const float* __restrict__ x,
                                              const float* __restrict__ w,
                                              const unsigned long long* __restrict__ keys,
                                              float* __restrict__ outq,
                                              float* __restrict__ outidx,
                                              double* __restrict__ part) {
  __shared__ int sidx[32];
  __shared__ double sp[4];
  const int b = blockIdx.x, t = threadIdx.x;

  if (t < 32) {
    const int row = b * 32 + t;
    unsigned long long k = keys[row];
    const int idx = (int)(unsigned int)(k & 0xFFFFFFFFull);
    outidx[row] = (float)idx;
    sidx[t] = idx;
  }
  __syncthreads();

  double acc = 0.0;
  const float4* x4 = (const float4*)x;
  float4* o4 = (float4*)outq;
#pragma unroll
  for (int i = 0; i < 2; ++i) {
    const int e = i * 256 + t;          // 0..511 float4s of this block's rows
    const int rl = e >> 4;              // local row (0..31)
    const int d4 = e & 15;              // float4 within the row
    const size_t gofs = ((size_t)b * 32 + rl) * 16 + d4;
    float4 xvv = x4[gofs];
    const float4* wr = (const float4*)(w + (size_t)sidx[rl] * DIM);
    float4 wv = wr[d4];
    float tx = wv.x - xvv.x, ty = wv.y - xvv.y;
    float tz = wv.z - xvv.z, tw = wv.w - xvv.w;
    float4 q;
    q.x = xvv.x + tx; q.y = xvv.y + ty;   // ref STE: x + fl(q - x)
    q.z = xvv.z + tz; q.w = xvv.w + tw;
    o4[gofs] = q;
    acc += (double)tx * tx + (double)ty * ty + (double)tz * tz + (double)tw * tw;
  }

#pragma unroll
  for (int s = 32; s > 0; s >>= 1) acc += __shfl_down(acc, s, 64);
  if ((t & 63) == 0) sp[t >> 6] = acc;
  __syncthreads();
  if (t == 0) part[b] = (sp[0] + sp[1]) + (sp[2] + sp[3]);
}

// Phase 4: reduce 1024 f64 block partials, commitment = 0.5 * mean.
__global__ __launch_bounds__(256) void vq_fin(const double* __restrict__ part,
                                              float* __restrict__ outloss) {
  __shared__ double sp[4];
  const int t = threadIdx.x;
  double a = (part[t] + part[t + 256]) + (part[t + 512] + part[t + 768]);
#pragma unroll
  for (int s = 32; s > 0; s >>= 1) a += __shfl_down(a, s, 64);
  if ((t & 63) == 0) sp[t >> 6] = a;
  __syncthreads();
  if (t == 0) {
    double total = (sp[0] + sp[1]) + (sp[2] + sp[3]);
    *outloss = 0.5f * (float)(total / (double)NELEM);
  }
}

extern "C" void kernel_launch(void* const* d_in, const int* in_sizes, int n_in,
                              void* d_out, int out_size, void* d_ws, size_t ws_size,
                              hipStream_t stream) {
  const float* x = (const float*)d_in[0];   // inputs (32,64,32,32) fp32
  const float* w = (const float*)d_in[1];   // weight (1024,64) fp32

  float* outq    = (float*)d_out;           // [0, 2097152)
  float* outidx  = outq + NELEM;            // [2097152, +32768)
  float* outloss = outidx + NROWS;          // [2129920]

  char* wsb = (char*)d_ws;
  float* se    = (float*)wsb;                                       // 4 KB   [0, 4096)
  double* part = (double*)(wsb + 4096);                             // 8 KB   [4096, 12288)
  float* sxv   = (float*)(wsb + 12288);                             // 128 KB [12288, 143360)
  unsigned long long* keys = (unsigned long long*)(wsb + 147456);   // 256 KB [147456, 409600)

  hipLaunchKernelGGL(vq_prep, dim3(128),  dim3(256), 0, stream, x, w, se, sxv, keys);
  hipLaunchKernelGGL(vq_dist, dim3(2048), dim3(256), 0, stream, x, w, se, sxv, keys);
  hipLaunchKernelGGL(vq_out,  dim3(1024), dim3(256), 0, stream, x, w, keys, outq, outidx, part);
  hipLaunchKernelGGL(vq_fin,  dim3(1),    dim3(256), 0, stream, part, outloss);
}